// Round 11
// baseline (385.380 us; speedup 1.0000x reference)
//
#include <hip/hip_runtime.h>
#include <hip/hip_bf16.h>
#include <hip/hip_fp16.h>
#include <math.h>

#define MAXDEG 512

typedef short v8s __attribute__((ext_vector_type(8)));
typedef float v4f __attribute__((ext_vector_type(4)));
typedef _Float16 h2 __attribute__((ext_vector_type(2)));

// ---------------- block reduce helpers ----------------
__device__ __forceinline__ float blockReduceSum(float v) {
    __shared__ float sh[8];
    int lane = threadIdx.x & 63, w = threadIdx.x >> 6;
    for (int o = 32; o > 0; o >>= 1) v += __shfl_down(v, o);
    __syncthreads();
    if (lane == 0) sh[w] = v;
    __syncthreads();
    if (w == 0) {
        int nw = (blockDim.x + 63) >> 6;
        v = (lane < nw) ? sh[lane] : 0.f;
        for (int o = 4; o > 0; o >>= 1) v += __shfl_down(v, o);
        if (lane == 0) sh[0] = v;
    }
    __syncthreads();
    return sh[0];
}

__device__ __forceinline__ float blockReduceMax(float v) {
    __shared__ float sh[8];
    int lane = threadIdx.x & 63, w = threadIdx.x >> 6;
    for (int o = 32; o > 0; o >>= 1) v = fmaxf(v, __shfl_down(v, o));
    __syncthreads();
    if (lane == 0) sh[w] = v;
    __syncthreads();
    if (w == 0) {
        int nw = (blockDim.x + 63) >> 6;
        v = (lane < nw) ? sh[lane] : -3.4e38f;
        for (int o = 4; o > 0; o >>= 1) v = fmaxf(v, __shfl_down(v, o));
        if (lane == 0) sh[0] = v;
    }
    __syncthreads();
    return sh[0];
}

__device__ __forceinline__ float leaky(float x) { return x >= 0.f ? x : 0.2f * x; }

// ---------------- kernels ----------------

// Small prep: [0,1024) hin x8-vec; [1024,1096) el/er zero; [1096,1304)
// LDS-tiled weight transposes. (CSR moved to gemm1_csr for overlap.)
__global__ void pre_small(const float* __restrict__ x, const int* __restrict__ obs,
                          const float* __restrict__ theta,
                          const float* __restrict__ Wh0, const float* __restrict__ Wh1,
                          const float* __restrict__ Wo0,
                          __half* __restrict__ hin, __half* __restrict__ Wh0t,
                          __half* __restrict__ Wh1t, __half* __restrict__ Wo0t,
                          float* __restrict__ elerZ, int elerN) {
    const int tid = threadIdx.x;
    int bb = blockIdx.x;
    if (bb < 1024) {                       // hin: 2M elems, 8 per thread
        int i8 = bb * 256 + tid;
        int n = i8 >> 6;
        int f = (i8 & 63) * 8;
        float4 a = *(const float4*)(x + (size_t)i8 * 8);
        float4 b = *(const float4*)(x + (size_t)i8 * 8 + 4);
        if (obs[n] == 1) {
            float4 ta = *(const float4*)(theta + f);
            float4 tb = *(const float4*)(theta + f + 4);
            a.x += ta.x; a.y += ta.y; a.z += ta.z; a.w += ta.w;
            b.x += tb.x; b.y += tb.y; b.z += tb.z; b.w += tb.w;
        }
        __half hv[8];
        hv[0] = __float2half(a.x); hv[1] = __float2half(a.y);
        hv[2] = __float2half(a.z); hv[3] = __float2half(a.w);
        hv[4] = __float2half(b.x); hv[5] = __float2half(b.y);
        hv[6] = __float2half(b.z); hv[7] = __float2half(b.w);
        *(uint4*)(hin + (size_t)i8 * 8) = *(const uint4*)hv;
        return;
    }
    bb -= 1024;
    if (bb < 72) {                         // el/er zero, float4
        int i = bb * 256 + tid;            // 72*256*4 = 73728 = elerN
        *(float4*)(elerZ + (size_t)i * 4) = make_float4(0.f, 0.f, 0.f, 0.f);
        return;
    }
    // ---- 64x64 LDS-tiled transposes (208 blocks) ----
    int t = bb - 72;
    const float* src;
    __half* dst;
    int srcStride, dstStride;
    if (t < 128) {                         // Wh0 [4][512][256] -> Wh0t [4][256][512]
        int b = t >> 5, tt = t & 31, kt = tt >> 2, mt = tt & 3;
        src = Wh0 + b * 131072 + (kt * 64) * 256 + mt * 64;
        dst = Wh0t + b * 131072 + (mt * 64) * 512 + kt * 64;
        srcStride = 256; dstStride = 512;
    } else if (t < 192) {                  // Wh1 [4][256][256] -> Wh1t [4][256][256]
        int u = t - 128;
        int b = u >> 4, tt = u & 15, kt = tt >> 2, mt = tt & 3;
        src = Wh1 + b * 65536 + (kt * 64) * 256 + mt * 64;
        dst = Wh1t + b * 65536 + (mt * 64) * 256 + kt * 64;
        srcStride = 256; dstStride = 256;
    } else {                               // Wo0 [1024][64] -> Wo0t [64][1024]
        int kt = t - 192;
        src = Wo0 + (kt * 64) * 64;
        dst = Wo0t + kt * 64;
        srcStride = 64; dstStride = 1024;
    }
    __shared__ float tile[64][65];
    int rr = tid >> 4;
    int cc = (tid & 15) * 4;
    #pragma unroll
    for (int sI = 0; sI < 4; sI++) {
        float4 v = *(const float4*)(src + (size_t)(rr + sI * 16) * srcStride + cc);
        tile[rr + sI * 16][cc]     = v.x;
        tile[rr + sI * 16][cc + 1] = v.y;
        tile[rr + sI * 16][cc + 2] = v.z;
        tile[rr + sI * 16][cc + 3] = v.w;
    }
    __syncthreads();
    int mr = tid >> 2;
    int kc = (tid & 3) * 16;
    #pragma unroll
    for (int g = 0; g < 2; g++) {
        v8s v;
        #pragma unroll
        for (int e = 0; e < 8; e++)
            v[e] = (short)__half_as_ushort(__float2half(tile[kc + g * 8 + e][mr]));
        *(v8s*)(dst + (size_t)mr * dstStride + kc + g * 8) = v;
    }
}

// Combined: blocks [0,4096) do CSR build + s_mat row sums (memory-bound);
// blocks [4096,4608) do the layer-1 64x128 MFMA GEMM (compute-bound).
// The two phases co-schedule on the CUs -> their times overlap instead of
// adding (gemm1 needs only hin/Wh0t; the CSR is needed only by attn1).
__global__ __launch_bounds__(256) void gemm1_csr(
    const __half* __restrict__ A, const __half* __restrict__ Bt,
    __half* __restrict__ C,
    const float* __restrict__ aVec, float* __restrict__ el, float* __restrict__ er,
    const float* __restrict__ adj, const float* __restrict__ s,
    int* __restrict__ colIdx, int* __restrict__ deg, float* __restrict__ dv,
    int N) {
    const int tid = threadIdx.x;
    if (blockIdx.x < 4096) {
        // ---------------- CSR + dv ----------------
        int row = blockIdx.x;
        __shared__ int cnt;
        if (tid == 0) cnt = 0;
        __syncthreads();
        const float4* ar = (const float4*)(adj + (size_t)row * N);
        const float4* sr = (const float4*)(s + (size_t)row * N);
        int* outp = colIdx + (size_t)row * MAXDEG;
        float psum = 0.f;
        const int n4 = N >> 2;
        for (int j4 = tid; j4 < n4; j4 += 256) {
            float4 a4 = ar[j4];
            float4 s4 = sr[j4];
            psum += (s4.x + s4.y) + (s4.z + s4.w);
            int jb = j4 << 2;
            if (a4.x > 0.f) { int p = atomicAdd(&cnt, 1); if (p < MAXDEG) outp[p] = jb; }
            if (a4.y > 0.f) { int p = atomicAdd(&cnt, 1); if (p < MAXDEG) outp[p] = jb + 1; }
            if (a4.z > 0.f) { int p = atomicAdd(&cnt, 1); if (p < MAXDEG) outp[p] = jb + 2; }
            if (a4.w > 0.f) { int p = atomicAdd(&cnt, 1); if (p < MAXDEG) outp[p] = jb + 3; }
        }
        psum = blockReduceSum(psum);
        __syncthreads();
        if (tid == 0) {
            deg[row] = cnt < MAXDEG ? cnt : MAXDEG;
            dv[row] = psum;
        }
        return;
    }
    // ---------------- layer-1 GEMM: hin[4096x512] @ Wh0t[b][256x512]^T ----
    const int g = blockIdx.x - 4096;       // 0..511
    const int bx = g & 1, by = (g >> 1) & 63, bz = g >> 7;
    const int K = 512, M = 256;
    const unsigned short* Ag = (const unsigned short*)A;
    const unsigned short* Bg = (const unsigned short*)Bt + (size_t)bz * 131072;
    __half* Cg = C + (size_t)bz * 4096 * 256;
    const float* av = aVec + (size_t)bz * 512;
    float* elb = el + (size_t)bz * 4096;
    float* erb = er + (size_t)bz * 4096;

    __shared__ __align__(16) unsigned short As[64][72];
    __shared__ __align__(16) unsigned short Bs[128][72];

    const int wave = tid >> 6, lane = tid & 63;
    const int wm = wave >> 1, wn = wave & 1;
    const int row0 = by * 64, col0 = bx * 128;
    const int lr = tid >> 2;
    const int lo = (tid & 3) * 16;
    const int m = lane & 15, quad = lane >> 4;

    v4f acc[2][4];
    #pragma unroll
    for (int i = 0; i < 2; i++)
        #pragma unroll
        for (int c = 0; c < 4; c++) acc[i][c] = (v4f)(0.f);

    for (int k0 = 0; k0 < K; k0 += 64) {
        *(int4*)(&As[lr][lo]) =
            *(const int4*)(Ag + (size_t)(row0 + lr) * K + k0 + lo);
        *(int4*)(&As[lr][lo + 8]) =
            *(const int4*)(Ag + (size_t)(row0 + lr) * K + k0 + lo + 8);
        *(int4*)(&Bs[lr][lo]) =
            *(const int4*)(Bg + (size_t)(col0 + lr) * K + k0 + lo);
        *(int4*)(&Bs[lr][lo + 8]) =
            *(const int4*)(Bg + (size_t)(col0 + lr) * K + k0 + lo + 8);
        *(int4*)(&Bs[lr + 64][lo]) =
            *(const int4*)(Bg + (size_t)(col0 + 64 + lr) * K + k0 + lo);
        *(int4*)(&Bs[lr + 64][lo + 8]) =
            *(const int4*)(Bg + (size_t)(col0 + 64 + lr) * K + k0 + lo + 8);
        __syncthreads();
        #pragma unroll
        for (int ks = 0; ks < 2; ks++) {
            v8s af[2], bfv[4];
            #pragma unroll
            for (int i = 0; i < 2; i++)
                af[i] = *(const v8s*)(&As[wm * 32 + i * 16 + m][ks * 32 + quad * 8]);
            #pragma unroll
            for (int c = 0; c < 4; c++)
                bfv[c] = *(const v8s*)(&Bs[wn * 64 + c * 16 + m][ks * 32 + quad * 8]);
            #pragma unroll
            for (int i = 0; i < 2; i++)
                #pragma unroll
                for (int c = 0; c < 4; c++)
                    acc[i][c] = __builtin_amdgcn_mfma_f32_16x16x32_f16(
                        af[i], bfv[c], acc[i][c], 0, 0, 0);
        }
        __syncthreads();
    }
    #pragma unroll
    for (int i = 0; i < 2; i++)
        #pragma unroll
        for (int c = 0; c < 4; c++)
            #pragma unroll
            for (int r = 0; r < 4; r++) {
                int row = row0 + wm * 32 + i * 16 + quad * 4 + r;
                int col = col0 + wn * 64 + c * 16 + m;
                Cg[(size_t)row * M + col] = __float2half(acc[i][c][r]);
            }
    float ael[4], aer[4];
    #pragma unroll
    for (int c = 0; c < 4; c++) {
        ael[c] = av[col0 + wn * 64 + c * 16 + m];
        aer[c] = av[M + col0 + wn * 64 + c * 16 + m];
    }
    #pragma unroll
    for (int i = 0; i < 2; i++)
        #pragma unroll
        for (int r = 0; r < 4; r++) {
            float pel = 0.f, per_ = 0.f;
            #pragma unroll
            for (int c = 0; c < 4; c++) {
                pel += acc[i][c][r] * ael[c];
                per_ += acc[i][c][r] * aer[c];
            }
            #pragma unroll
            for (int off = 1; off < 16; off <<= 1) {
                pel += __shfl_xor(pel, off);
                per_ += __shfl_xor(per_, off);
            }
            if (m == 0) {
                int row = row0 + wm * 32 + i * 16 + quad * 4 + r;
                atomicAdd(&elb[row], pel);
                atomicAdd(&erb[row], per_);
            }
        }
}

// 64x128 block-tile MFMA GEMM, BK=64, 2x2 wave layout (layer 2).
__global__ __launch_bounds__(256) void gemm_mfma64x128(
    const __half* __restrict__ A, const __half* __restrict__ Bt,
    __half* __restrict__ C, int N, int K, int M,
    size_t sA, size_t sB, size_t sC,
    const float* __restrict__ aVec, size_t aStride,
    float* __restrict__ el, float* __restrict__ er) {
    int b = blockIdx.z;
    const unsigned short* Ag = (const unsigned short*)(A + (size_t)b * sA);
    const unsigned short* Bg = (const unsigned short*)(Bt + (size_t)b * sB);
    __half* Cg = C + (size_t)b * sC;
    const float* av = aVec + (size_t)b * aStride;

    __shared__ __align__(16) unsigned short As[64][72];
    __shared__ __align__(16) unsigned short Bs[128][72];

    const int tid = threadIdx.x;
    const int wave = tid >> 6, lane = tid & 63;
    const int wm = wave >> 1, wn = wave & 1;
    const int row0 = blockIdx.y * 64, col0 = blockIdx.x * 128;
    const int lr = tid >> 2;
    const int lo = (tid & 3) * 16;
    const int m = lane & 15, quad = lane >> 4;

    v4f acc[2][4];
    #pragma unroll
    for (int i = 0; i < 2; i++)
        #pragma unroll
        for (int c = 0; c < 4; c++) acc[i][c] = (v4f)(0.f);

    for (int k0 = 0; k0 < K; k0 += 64) {
        *(int4*)(&As[lr][lo]) =
            *(const int4*)(Ag + (size_t)(row0 + lr) * K + k0 + lo);
        *(int4*)(&As[lr][lo + 8]) =
            *(const int4*)(Ag + (size_t)(row0 + lr) * K + k0 + lo + 8);
        *(int4*)(&Bs[lr][lo]) =
            *(const int4*)(Bg + (size_t)(col0 + lr) * K + k0 + lo);
        *(int4*)(&Bs[lr][lo + 8]) =
            *(const int4*)(Bg + (size_t)(col0 + lr) * K + k0 + lo + 8);
        *(int4*)(&Bs[lr + 64][lo]) =
            *(const int4*)(Bg + (size_t)(col0 + 64 + lr) * K + k0 + lo);
        *(int4*)(&Bs[lr + 64][lo + 8]) =
            *(const int4*)(Bg + (size_t)(col0 + 64 + lr) * K + k0 + lo + 8);
        __syncthreads();
        #pragma unroll
        for (int ks = 0; ks < 2; ks++) {
            v8s af[2], bfv[4];
            #pragma unroll
            for (int i = 0; i < 2; i++)
                af[i] = *(const v8s*)(&As[wm * 32 + i * 16 + m][ks * 32 + quad * 8]);
            #pragma unroll
            for (int c = 0; c < 4; c++)
                bfv[c] = *(const v8s*)(&Bs[wn * 64 + c * 16 + m][ks * 32 + quad * 8]);
            #pragma unroll
            for (int i = 0; i < 2; i++)
                #pragma unroll
                for (int c = 0; c < 4; c++)
                    acc[i][c] = __builtin_amdgcn_mfma_f32_16x16x32_f16(
                        af[i], bfv[c], acc[i][c], 0, 0, 0);
        }
        __syncthreads();
    }
    #pragma unroll
    for (int i = 0; i < 2; i++)
        #pragma unroll
        for (int c = 0; c < 4; c++)
            #pragma unroll
            for (int r = 0; r < 4; r++) {
                int row = row0 + wm * 32 + i * 16 + quad * 4 + r;
                int col = col0 + wn * 64 + c * 16 + m;
                Cg[(size_t)row * M + col] = __float2half(acc[i][c][r]);
            }
    float ael[4], aer[4];
    #pragma unroll
    for (int c = 0; c < 4; c++) {
        ael[c] = av[col0 + wn * 64 + c * 16 + m];
        aer[c] = av[M + col0 + wn * 64 + c * 16 + m];
    }
    #pragma unroll
    for (int i = 0; i < 2; i++)
        #pragma unroll
        for (int r = 0; r < 4; r++) {
            float pel = 0.f, per_ = 0.f;
            #pragma unroll
            for (int c = 0; c < 4; c++) {
                pel += acc[i][c][r] * ael[c];
                per_ += acc[i][c][r] * aer[c];
            }
            #pragma unroll
            for (int off = 1; off < 16; off <<= 1) {
                pel += __shfl_xor(pel, off);
                per_ += __shfl_xor(per_, off);
            }
            if (m == 0) {
                int row = row0 + wm * 32 + i * 16 + quad * 4 + r;
                atomicAdd(&el[(size_t)b * N + row], pel);
                atomicAdd(&er[(size_t)b * N + row], per_);
            }
        }
}

// 16-row tile GEMM for the M=64 output layer (K=1024), grid=256 blocks.
__global__ __launch_bounds__(256) void gemm_mfma16(
    const __half* __restrict__ A, const __half* __restrict__ Bt,
    __half* __restrict__ C, int N, int K, int M,
    const float* __restrict__ aVec,
    float* __restrict__ el, float* __restrict__ er) {
    const unsigned short* Ag = (const unsigned short*)A;
    const unsigned short* Bg = (const unsigned short*)Bt;
    __half* Cg = C;
    const float* av = aVec;

    __shared__ __align__(16) unsigned short As[16][72];
    __shared__ __align__(16) unsigned short Bs[64][72];

    const int tid = threadIdx.x;
    const int wave = tid >> 6, lane = tid & 63;
    const int row0 = blockIdx.y * 16;
    const int m = lane & 15, quad = lane >> 4;

    v4f acc = (v4f)(0.f);

    for (int k0 = 0; k0 < K; k0 += 64) {
        if (tid < 128) {
            int ar = tid >> 3, ac = (tid & 7) * 8;
            *(int4*)(&As[ar][ac]) =
                *(const int4*)(Ag + (size_t)(row0 + ar) * K + k0 + ac);
        }
        {
            int br = tid >> 2, bc = (tid & 3) * 16;
            *(int4*)(&Bs[br][bc]) =
                *(const int4*)(Bg + (size_t)br * K + k0 + bc);
            *(int4*)(&Bs[br][bc + 8]) =
                *(const int4*)(Bg + (size_t)br * K + k0 + bc + 8);
        }
        __syncthreads();
        #pragma unroll
        for (int ks = 0; ks < 2; ks++) {
            v8s af = *(const v8s*)(&As[m][ks * 32 + quad * 8]);
            v8s bf = *(const v8s*)(&Bs[wave * 16 + m][ks * 32 + quad * 8]);
            acc = __builtin_amdgcn_mfma_f32_16x16x32_f16(af, bf, acc, 0, 0, 0);
        }
        __syncthreads();
    }
    #pragma unroll
    for (int r = 0; r < 4; r++) {
        int row = row0 + quad * 4 + r;
        int col = wave * 16 + m;
        Cg[(size_t)row * M + col] = __float2half(acc[r]);
    }
    float ael = av[wave * 16 + m];
    float aer = av[M + wave * 16 + m];
    #pragma unroll
    for (int r = 0; r < 4; r++) {
        float pel = acc[r] * ael;
        float per_ = acc[r] * aer;
        #pragma unroll
        for (int off = 1; off < 16; off <<= 1) {
            pel += __shfl_xor(pel, off);
            per_ += __shfl_xor(per_, off);
        }
        if (m == 0) {
            int row = row0 + quad * 4 + r;
            atomicAdd(&el[row], pel);
            atomicAdd(&er[row], per_);
        }
    }
}

// Masked softmax + fp16 gather. Two waves/block, wave-per-task, XCD-pinned.
// attn_vec<256> is at its scattered-gather ceiling (~22 TB/s effective L2).
template<int D, int ACT, int HEADS, int FUSE>
__global__ __launch_bounds__(128) void attn_vec(
    const __half* __restrict__ Wh, const float* __restrict__ el,
    const float* __restrict__ er, const int* __restrict__ colIdx,
    const int* __restrict__ deg, __half* __restrict__ out,
    int N, size_t sWh, size_t sOut, int outRowStride,
    const float* __restrict__ wo1, const float* __restrict__ ao1,
    float* __restrict__ o2wh, float* __restrict__ el4, float* __restrict__ er4) {
    constexpr int LPN = D / 8;
    constexpr int SUBS = 64 / LPN;
    constexpr int PER_WAVE = SUBS * 4;
    constexpr int STEP = PER_WAVE * 2;

    const int tid = threadIdx.x;
    const int wave = tid >> 6, lane = tid & 63;
    int b, row;
    if (HEADS == 4) {
        int xcd = blockIdx.x & 7;
        b = xcd >> 1;
        row = ((xcd & 1) << 11) + ((blockIdx.x >> 3) << 1) + wave;
    } else {
        b = 0;
        row = blockIdx.x * 2 + wave;
    }

    const __half* whb = Wh + (size_t)b * sWh;
    const float* erb = er + (size_t)b * N;
    const float eln = el[(size_t)b * N + row];
    const int dc = deg[row];
    const int dcp = (dc + STEP - 1) & ~(STEP - 1);
    const int* ci = colIdx + (size_t)row * MAXDEG;

    __shared__ __align__(16) float2 spc[2][MAXDEG];
    float2* sp = spc[wave];

    float sreg[8];
    int jreg[8];
    float mx = -3.4e38f;
    #pragma unroll
    for (int s8 = 0; s8 < 8; s8++) {
        int k = s8 * 64 + lane;
        if (k < dc) {
            int j = ci[k];
            float s = eln + erb[j];
            s = fmaxf(s, 0.2f * s);
            sreg[s8] = s;
            jreg[s8] = j * (D * 2);
            mx = fmaxf(mx, s);
        }
    }
    #pragma unroll
    for (int off = 1; off < 64; off <<= 1) mx = fmaxf(mx, __shfl_xor(mx, off));

    float l = 0.f;
    #pragma unroll
    for (int s8 = 0; s8 < 8; s8++) {
        int k = s8 * 64 + lane;
        if (k < dc) {
            float p = __expf(sreg[s8] - mx);
            l += p;
            unsigned int pu = __half_as_ushort(__float2half(p));
            sp[k] = make_float2(__int_as_float(pu | (pu << 16)),
                                __int_as_float(jreg[s8]));
        }
    }
    for (int k = dc + lane; k < dcp; k += 64)
        sp[k] = make_float2(__int_as_float(0), __int_as_float(0));
    #pragma unroll
    for (int off = 1; off < 64; off <<= 1) l += __shfl_xor(l, off);
    const float inv = 1.f / l;

    asm volatile("s_waitcnt lgkmcnt(0)" ::: "memory");

    const int sub = lane / LPN;
    const int dl = (lane % LPN) * 8;
    const char* wp = (const char*)(whb + dl);

    union HU { unsigned int u; h2 h; };
    union R4 { uint4 u; h2 h[4]; };

    h2 a0[4], a1[4], a2[4], a3[4];
    #pragma unroll
    for (int i = 0; i < 4; i++) {
        a0[i] = (h2)(_Float16)0; a1[i] = (h2)(_Float16)0;
        a2[i] = (h2)(_Float16)0; a3[i] = (h2)(_Float16)0;
    }

    for (int k = sub * 4; k < dcp; k += STEP) {
        float4 pA = *(const float4*)(&sp[k]);
        float4 pB = *(const float4*)(&sp[k + 2]);
        float4 pC = *(const float4*)(&sp[k + PER_WAVE]);
        float4 pD = *(const float4*)(&sp[k + PER_WAVE + 2]);
        R4 r0, r1, r2, r3, r4, r5, r6, r7;
        r0.u = *(const uint4*)(wp + __float_as_int(pA.y));
        r1.u = *(const uint4*)(wp + __float_as_int(pA.w));
        r2.u = *(const uint4*)(wp + __float_as_int(pB.y));
        r3.u = *(const uint4*)(wp + __float_as_int(pB.w));
        r4.u = *(const uint4*)(wp + __float_as_int(pC.y));
        r5.u = *(const uint4*)(wp + __float_as_int(pC.w));
        r6.u = *(const uint4*)(wp + __float_as_int(pD.y));
        r7.u = *(const uint4*)(wp + __float_as_int(pD.w));
        HU p0, p1, p2, p3, p4, p5, p6, p7;
        p0.u = __float_as_int(pA.x);
        p1.u = __float_as_int(pA.z);
        p2.u = __float_as_int(pB.x);
        p3.u = __float_as_int(pB.z);
        p4.u = __float_as_int(pC.x);
        p5.u = __float_as_int(pC.z);
        p6.u = __float_as_int(pD.x);
        p7.u = __float_as_int(pD.z);
        #pragma unroll
        for (int i = 0; i < 4; i++) {
            a0[i] += p0.h * r0.h[i];
            a1[i] += p2.h * r2.h[i];
            a2[i] += p4.h * r4.h[i];
            a3[i] += p6.h * r6.h[i];
        }
        #pragma unroll
        for (int i = 0; i < 4; i++) {
            a0[i] += p1.h * r1.h[i];
            a1[i] += p3.h * r3.h[i];
            a2[i] += p5.h * r5.h[i];
            a3[i] += p7.h * r7.h[i];
        }
    }
    #pragma unroll
    for (int i = 0; i < 4; i++) a0[i] += (a1[i] + (a2[i] + a3[i]));
    #pragma unroll
    for (int off = LPN; off < 64; off <<= 1)
        #pragma unroll
        for (int i = 0; i < 4; i++) {
            HU t, s;
            t.h = a0[i];
            s.u = __shfl_xor((int)t.u, off);
            a0[i] += s.h;
        }

    if (FUSE) {
        if (sub == 0) {
            float t = 0.f;
            #pragma unroll
            for (int i = 0; i < 4; i++) {
                t += (float)a0[i][0] * inv * wo1[dl + 2 * i];
                t += (float)a0[i][1] * inv * wo1[dl + 2 * i + 1];
            }
            #pragma unroll
            for (int off = 1; off < LPN; off <<= 1) t += __shfl_xor(t, off);
            if (lane == 0) {
                o2wh[row] = t;
                el4[row] = t * ao1[0];
                er4[row] = t * ao1[1];
            }
        }
        return;
    }
    if (sub == 0) {
        __half hv[8];
        #pragma unroll
        for (int i = 0; i < 4; i++) {
            float v0 = (float)a0[i][0] * inv;
            float v1 = (float)a0[i][1] * inv;
            if (ACT == 1) {
                v0 = (v0 > 0.f) ? v0 : expm1f(v0);
                v1 = (v1 > 0.f) ? v1 : expm1f(v1);
            }
            hv[2 * i]     = __float2half(v0);
            hv[2 * i + 1] = __float2half(v1);
        }
        *(uint4*)(out + (size_t)b * sOut + (size_t)row * outRowStride + dl) =
            *(const uint4*)hv;
    }
}

// D==1 attention + elu + degreeNN fused (one block per row).
__global__ void attn_d1_deg(const float* __restrict__ o2wh, const float* __restrict__ el,
                            const float* __restrict__ er, const int* __restrict__ colIdx,
                            const int* __restrict__ deg, const float* __restrict__ dv,
                            const float* __restrict__ dW, const float* __restrict__ dW0,
                            const float* __restrict__ dW1, const float* __restrict__ dW01,
                            const float* __restrict__ dW2, const float* __restrict__ dW02,
                            const float* __restrict__ dV, const float* __restrict__ dV0,
                            float* __restrict__ out, int N) {
    int row = blockIdx.x, tid = threadIdx.x;
    const float eln = el[row];
    const int dc = deg[row];
    const int* ci = colIdx + (size_t)row * MAXDEG;
    __shared__ float sp[MAXDEG];
    __shared__ int sc[MAXDEG];
    float mx = -3.4e38f;
    for (int k = tid; k < dc; k += blockDim.x) {
        int j = ci[k];
        sc[k] = j;
        float s = eln + er[j];
        s = fmaxf(s, 0.2f * s);
        sp[k] = s;
        mx = fmaxf(mx, s);
    }
    mx = blockReduceMax(mx);
    float l = 0.f, acc = 0.f;
    for (int k = tid; k < dc; k += blockDim.x) {
        float p = __expf(sp[k] - mx);
        l += p;
        acc += p * o2wh[sc[k]];
    }
    l = blockReduceSum(l);
    acc = blockReduceSum(acc);
    if (tid == 0) {
        float h = acc / l;
        h = (h > 0.f) ? h : expm1f(h);
        float d = dv[row];
        float t0[10], t1[20], t2[10];
        #pragma unroll
        for (int i = 0; i < 10; i++)
            t0[i] = leaky(h * dW[i] + d * dW[10 + i] + dW0[i]);
        #pragma unroll
        for (int j = 0; j < 20; j++) {
            float s = dW01[j];
            #pragma unroll
            for (int i = 0; i < 10; i++) s += t0[i] * dW1[i * 20 + j];
            t1[j] = leaky(s);
        }
        #pragma unroll
        for (int j = 0; j < 10; j++) {
            float s = dW02[j];
            #pragma unroll
            for (int i = 0; i < 20; i++) s += t1[i] * dW2[i * 10 + j];
            t2[j] = leaky(s);
        }
        float o = dV0[0];
        #pragma unroll
        for (int i = 0; i < 10; i++) o += t2[i] * dV[i];
        out[row] = leaky(o);
    }
}

// ---------------- launch ----------------
extern "C" void kernel_launch(void* const* d_in, const int* in_sizes, int n_in,
                              void* d_out, int out_size, void* d_ws, size_t ws_size,
                              hipStream_t stream) {
    const int N = 4096, F = 512, H = 4, D1 = 256, O1 = 64;
    const float* x     = (const float*)d_in[0];
    const float* adj   = (const float*)d_in[1];
    const int*   obs   = (const int*)  d_in[2];
    const float* s_mat = (const float*)d_in[3];
    const float* theta = (const float*)d_in[4];
    const float* Wh0   = (const float*)d_in[5];
    const float* ah0   = (const float*)d_in[6];
    const float* Wh1   = (const float*)d_in[7];
    const float* ah1   = (const float*)d_in[8];
    const float* Wo0   = (const float*)d_in[9];
    const float* ao0   = (const float*)d_in[10];
    const float* Wo1   = (const float*)d_in[11];
    const float* ao1   = (const float*)d_in[12];
    const float* dWp   = (const float*)d_in[13];
    const float* dW0p  = (const float*)d_in[14];
    const float* dW1p  = (const float*)d_in[15];
    const float* dW01p = (const float*)d_in[16];
    const float* dW2p  = (const float*)d_in[17];
    const float* dW02p = (const float*)d_in[18];
    const float* dVp   = (const float*)d_in[19];
    const float* dV0p  = (const float*)d_in[20];
    float* outp = (float*)d_out;

    char* ws = (char*)d_ws;
    auto alloc = [&](size_t bytes) {
        char* p = ws;
        ws += (bytes + 255) & ~(size_t)255;
        return p;
    };
    __half* hin  = (__half*)alloc((size_t)N * F * 2);
    __half* whA  = (__half*)alloc((size_t)H * N * D1 * 2);
    __half* hb   = (__half*)alloc((size_t)H * N * D1 * 2);
    __half* hcat = (__half*)alloc((size_t)N * H * D1 * 2);
    __half* o1Wh = (__half*)alloc((size_t)N * O1 * 2);
    float* o2Wh  = (float*)alloc((size_t)N * 4);
    __half* Wh0t = (__half*)alloc((size_t)H * F * D1 * 2);
    __half* Wh1t = (__half*)alloc((size_t)H * D1 * D1 * 2);
    __half* Wo0t = (__half*)alloc((size_t)H * D1 * O1 * 2);
    int elerN = 4 * H * N + 2 * N;
    float* elerZ = (float*)alloc((size_t)elerN * 4);
    float* el1 = elerZ;
    float* er1 = el1 + H * N;
    float* el2 = er1 + H * N;
    float* er2 = el2 + H * N;
    float* el3 = er2 + H * N;
    float* er3 = el3 + N;
    float* el4 = (float*)alloc((size_t)N * 4);
    float* er4 = (float*)alloc((size_t)N * 4);
    float* dv  = (float*)alloc((size_t)N * 4);
    int* colIdx = (int*)alloc((size_t)N * MAXDEG * 4);
    int* deg    = (int*)alloc((size_t)N * 4);

    // ----- prep (hin, transposes, zeroing) -----
    pre_small<<<1024 + 72 + 208, 256, 0, stream>>>(
        x, obs, theta, Wh0, Wh1, Wo0, hin, Wh0t, Wh1t, Wo0t, elerZ, elerN);

    // ----- CSR build (4096 blocks) ∥ multi-head layer-1 GEMM (512 blocks) -----
    gemm1_csr<<<4096 + 512, 256, 0, stream>>>(
        hin, Wh0t, whA, ah0, el1, er1,
        adj, s_mat, colIdx, deg, dv, N);
    attn_vec<256, 1, 4, 0><<<(N * H) / 2, 128, 0, stream>>>(
        whA, el1, er1, colIdx, deg, hb,
        N, (size_t)N * D1, (size_t)N * D1, D1,
        nullptr, nullptr, nullptr, nullptr, nullptr);

    // ----- multi-head layer 2 (D=256, elu) -> hcat interleaved -----
    gemm_mfma64x128<<<dim3(D1 / 128, N / 64, H), 256, 0, stream>>>(
        hb, Wh1t, whA, N, D1, D1, (size_t)N * D1, (size_t)D1 * D1, (size_t)N * D1,
        ah1, (size_t)2 * D1, el2, er2);
    attn_vec<256, 1, 4, 0><<<(N * H) / 2, 128, 0, stream>>>(
        whA, el2, er2, colIdx, deg, hcat,
        N, (size_t)N * D1, (size_t)D1, H * D1,
        nullptr, nullptr, nullptr, nullptr, nullptr);

    // ----- output layer 1 (D=64, no act) + fused matvec (Wo1) -----
    gemm_mfma16<<<dim3(1, N / 16, 1), 256, 0, stream>>>(
        hcat, Wo0t, o1Wh, N, H * D1, O1,
        ao0, el3, er3);
    attn_vec<64, 0, 1, 1><<<N / 2, 128, 0, stream>>>(
        o1Wh, el3, er3, colIdx, deg, nullptr,
        N, 0, 0, O1,
        Wo1, ao1, o2Wh, el4, er4);

    // ----- output layer 2 (D=1) + elu + degreeNN -----
    attn_d1_deg<<<N, 256, 0, stream>>>(o2Wh, el4, er4, colIdx, deg, dv,
        dWp, dW0p, dW1p, dW01p, dW2p, dW02p, dVp, dV0p, outp, N);
}

// Round 12
// 375.432 us; speedup vs baseline: 1.0265x; 1.0265x over previous
//
#include <hip/hip_runtime.h>
#include <hip/hip_bf16.h>
#include <hip/hip_fp16.h>
#include <math.h>

#define MAXDEG 512

typedef short v8s __attribute__((ext_vector_type(8)));
typedef float v4f __attribute__((ext_vector_type(4)));
typedef _Float16 h2 __attribute__((ext_vector_type(2)));

// ---------------- block reduce helpers ----------------
__device__ __forceinline__ float blockReduceSum(float v) {
    __shared__ float sh[8];
    int lane = threadIdx.x & 63, w = threadIdx.x >> 6;
    for (int o = 32; o > 0; o >>= 1) v += __shfl_down(v, o);
    __syncthreads();
    if (lane == 0) sh[w] = v;
    __syncthreads();
    if (w == 0) {
        int nw = (blockDim.x + 63) >> 6;
        v = (lane < nw) ? sh[lane] : 0.f;
        for (int o = 4; o > 0; o >>= 1) v += __shfl_down(v, o);
        if (lane == 0) sh[0] = v;
    }
    __syncthreads();
    return sh[0];
}

__device__ __forceinline__ float blockReduceMax(float v) {
    __shared__ float sh[8];
    int lane = threadIdx.x & 63, w = threadIdx.x >> 6;
    for (int o = 32; o > 0; o >>= 1) v = fmaxf(v, __shfl_down(v, o));
    __syncthreads();
    if (lane == 0) sh[w] = v;
    __syncthreads();
    if (w == 0) {
        int nw = (blockDim.x + 63) >> 6;
        v = (lane < nw) ? sh[lane] : -3.4e38f;
        for (int o = 4; o > 0; o >>= 1) v = fmaxf(v, __shfl_down(v, o));
        if (lane == 0) sh[0] = v;
    }
    __syncthreads();
    return sh[0];
}

__device__ __forceinline__ float leaky(float x) { return x >= 0.f ? x : 0.2f * x; }

// ---------------- kernels ----------------

// Small prep: [0,1024) hin x8-vec; [1024,1096) el/er zero; [1096,1304)
// LDS-tiled weight transposes. (CSR lives in gemm1_csr for overlap.)
__global__ void pre_small(const float* __restrict__ x, const int* __restrict__ obs,
                          const float* __restrict__ theta,
                          const float* __restrict__ Wh0, const float* __restrict__ Wh1,
                          const float* __restrict__ Wo0,
                          __half* __restrict__ hin, __half* __restrict__ Wh0t,
                          __half* __restrict__ Wh1t, __half* __restrict__ Wo0t,
                          float* __restrict__ elerZ, int elerN) {
    const int tid = threadIdx.x;
    int bb = blockIdx.x;
    if (bb < 1024) {                       // hin: 2M elems, 8 per thread
        int i8 = bb * 256 + tid;
        int n = i8 >> 6;
        int f = (i8 & 63) * 8;
        float4 a = *(const float4*)(x + (size_t)i8 * 8);
        float4 b = *(const float4*)(x + (size_t)i8 * 8 + 4);
        if (obs[n] == 1) {
            float4 ta = *(const float4*)(theta + f);
            float4 tb = *(const float4*)(theta + f + 4);
            a.x += ta.x; a.y += ta.y; a.z += ta.z; a.w += ta.w;
            b.x += tb.x; b.y += tb.y; b.z += tb.z; b.w += tb.w;
        }
        __half hv[8];
        hv[0] = __float2half(a.x); hv[1] = __float2half(a.y);
        hv[2] = __float2half(a.z); hv[3] = __float2half(a.w);
        hv[4] = __float2half(b.x); hv[5] = __float2half(b.y);
        hv[6] = __float2half(b.z); hv[7] = __float2half(b.w);
        *(uint4*)(hin + (size_t)i8 * 8) = *(const uint4*)hv;
        return;
    }
    bb -= 1024;
    if (bb < 72) {                         // el/er zero, float4
        int i = bb * 256 + tid;            // 72*256*4 = 73728 = elerN
        *(float4*)(elerZ + (size_t)i * 4) = make_float4(0.f, 0.f, 0.f, 0.f);
        return;
    }
    // ---- 64x64 LDS-tiled transposes (208 blocks) ----
    int t = bb - 72;
    const float* src;
    __half* dst;
    int srcStride, dstStride;
    if (t < 128) {                         // Wh0 [4][512][256] -> Wh0t [4][256][512]
        int b = t >> 5, tt = t & 31, kt = tt >> 2, mt = tt & 3;
        src = Wh0 + b * 131072 + (kt * 64) * 256 + mt * 64;
        dst = Wh0t + b * 131072 + (mt * 64) * 512 + kt * 64;
        srcStride = 256; dstStride = 512;
    } else if (t < 192) {                  // Wh1 [4][256][256] -> Wh1t [4][256][256]
        int u = t - 128;
        int b = u >> 4, tt = u & 15, kt = tt >> 2, mt = tt & 3;
        src = Wh1 + b * 65536 + (kt * 64) * 256 + mt * 64;
        dst = Wh1t + b * 65536 + (mt * 64) * 256 + kt * 64;
        srcStride = 256; dstStride = 256;
    } else {                               // Wo0 [1024][64] -> Wo0t [64][1024]
        int kt = t - 192;
        src = Wo0 + (kt * 64) * 64;
        dst = Wo0t + kt * 64;
        srcStride = 64; dstStride = 1024;
    }
    __shared__ float tile[64][65];
    int rr = tid >> 4;
    int cc = (tid & 15) * 4;
    #pragma unroll
    for (int sI = 0; sI < 4; sI++) {
        float4 v = *(const float4*)(src + (size_t)(rr + sI * 16) * srcStride + cc);
        tile[rr + sI * 16][cc]     = v.x;
        tile[rr + sI * 16][cc + 1] = v.y;
        tile[rr + sI * 16][cc + 2] = v.z;
        tile[rr + sI * 16][cc + 3] = v.w;
    }
    __syncthreads();
    int mr = tid >> 2;
    int kc = (tid & 3) * 16;
    #pragma unroll
    for (int g = 0; g < 2; g++) {
        v8s v;
        #pragma unroll
        for (int e = 0; e < 8; e++)
            v[e] = (short)__half_as_ushort(__float2half(tile[kc + g * 8 + e][mr]));
        *(v8s*)(dst + (size_t)mr * dstStride + kc + g * 8) = v;
    }
}

// Combined: blocks [0,512) do the layer-1 64x128 MFMA GEMM (dispatched FIRST
// so they fill CUs immediately); blocks [512,4608) do CSR build + s_mat row
// sums. BK=32 keeps LDS at 15.4KB. CSR preloads all 8 float4s upfront (8
// outstanding loads/lane) and compacts hits via wave-ballot (one LDS atomic
// per ballot instead of a serialized per-lane atomic chain).
__global__ __launch_bounds__(256) void gemm1_csr(
    const __half* __restrict__ A, const __half* __restrict__ Bt,
    __half* __restrict__ C,
    const float* __restrict__ aVec, float* __restrict__ el, float* __restrict__ er,
    const float* __restrict__ adj, const float* __restrict__ s,
    int* __restrict__ colIdx, int* __restrict__ deg, float* __restrict__ dv,
    int N) {
    const int tid = threadIdx.x;
    const int lane = tid & 63;
    if (blockIdx.x >= 512) {
        // ---------------- CSR + dv ----------------
        int row = blockIdx.x - 512;
        __shared__ int cnt;
        if (tid == 0) cnt = 0;
        __syncthreads();
        const float4* ar = (const float4*)(adj + (size_t)row * N);
        const float4* sr = (const float4*)(s + (size_t)row * N);
        int* outp = colIdx + (size_t)row * MAXDEG;
        // preload all 8 vectors -> 8 outstanding dwordx4 per lane
        float4 aa[4], ss[4];
        #pragma unroll
        for (int it = 0; it < 4; it++) {
            aa[it] = ar[tid + it * 256];
            ss[it] = sr[tid + it * 256];
        }
        float psum = 0.f;
        #pragma unroll
        for (int it = 0; it < 4; it++)
            psum += (ss[it].x + ss[it].y) + (ss[it].z + ss[it].w);
        // ballot-compacted emission
        #pragma unroll
        for (int it = 0; it < 4; it++) {
            int jb = (tid + it * 256) << 2;
            float vals[4] = {aa[it].x, aa[it].y, aa[it].z, aa[it].w};
            #pragma unroll
            for (int c = 0; c < 4; c++) {
                bool hit = vals[c] > 0.f;
                unsigned long long mb = __ballot(hit);
                if (mb) {
                    int base = 0;
                    if (lane == 0) base = atomicAdd(&cnt, __popcll(mb));
                    base = __shfl(base, 0);
                    if (hit) {
                        int p = base + __popcll(mb & ((1ull << lane) - 1ull));
                        if (p < MAXDEG) outp[p] = jb + c;
                    }
                }
            }
        }
        psum = blockReduceSum(psum);
        __syncthreads();
        if (tid == 0) {
            deg[row] = cnt < MAXDEG ? cnt : MAXDEG;
            dv[row] = psum;
        }
        return;
    }
    // ------- layer-1 GEMM: hin[4096x512] @ Wh0t[b][256x512]^T, BK=32 -------
    const int g = blockIdx.x;              // 0..511
    const int bx = g & 1, by = (g >> 1) & 63, bz = g >> 7;
    const int K = 512, M = 256;
    const unsigned short* Ag = (const unsigned short*)A;
    const unsigned short* Bg = (const unsigned short*)Bt + (size_t)bz * 131072;
    __half* Cg = C + (size_t)bz * 4096 * 256;
    const float* av = aVec + (size_t)bz * 512;
    float* elb = el + (size_t)bz * 4096;
    float* erb = er + (size_t)bz * 4096;

    __shared__ __align__(16) unsigned short As[64][40];
    __shared__ __align__(16) unsigned short Bs[128][40];

    const int wave = tid >> 6;
    const int wm = wave >> 1, wn = wave & 1;
    const int row0 = by * 64, col0 = bx * 128;
    const int lr = tid >> 2;
    const int lo = (tid & 3) * 8;
    const int m = lane & 15, quad = lane >> 4;

    v4f acc[2][4];
    #pragma unroll
    for (int i = 0; i < 2; i++)
        #pragma unroll
        for (int c = 0; c < 4; c++) acc[i][c] = (v4f)(0.f);

    for (int k0 = 0; k0 < K; k0 += 32) {
        *(int4*)(&As[lr][lo]) =
            *(const int4*)(Ag + (size_t)(row0 + lr) * K + k0 + lo);
        *(int4*)(&Bs[lr][lo]) =
            *(const int4*)(Bg + (size_t)(col0 + lr) * K + k0 + lo);
        *(int4*)(&Bs[lr + 64][lo]) =
            *(const int4*)(Bg + (size_t)(col0 + 64 + lr) * K + k0 + lo);
        __syncthreads();
        v8s af[2], bfv[4];
        #pragma unroll
        for (int i = 0; i < 2; i++)
            af[i] = *(const v8s*)(&As[wm * 32 + i * 16 + m][quad * 8]);
        #pragma unroll
        for (int c = 0; c < 4; c++)
            bfv[c] = *(const v8s*)(&Bs[wn * 64 + c * 16 + m][quad * 8]);
        #pragma unroll
        for (int i = 0; i < 2; i++)
            #pragma unroll
            for (int c = 0; c < 4; c++)
                acc[i][c] = __builtin_amdgcn_mfma_f32_16x16x32_f16(
                    af[i], bfv[c], acc[i][c], 0, 0, 0);
        __syncthreads();
    }
    #pragma unroll
    for (int i = 0; i < 2; i++)
        #pragma unroll
        for (int c = 0; c < 4; c++)
            #pragma unroll
            for (int r = 0; r < 4; r++) {
                int row = row0 + wm * 32 + i * 16 + quad * 4 + r;
                int col = col0 + wn * 64 + c * 16 + m;
                Cg[(size_t)row * M + col] = __float2half(acc[i][c][r]);
            }
    float ael[4], aer[4];
    #pragma unroll
    for (int c = 0; c < 4; c++) {
        ael[c] = av[col0 + wn * 64 + c * 16 + m];
        aer[c] = av[M + col0 + wn * 64 + c * 16 + m];
    }
    #pragma unroll
    for (int i = 0; i < 2; i++)
        #pragma unroll
        for (int r = 0; r < 4; r++) {
            float pel = 0.f, per_ = 0.f;
            #pragma unroll
            for (int c = 0; c < 4; c++) {
                pel += acc[i][c][r] * ael[c];
                per_ += acc[i][c][r] * aer[c];
            }
            #pragma unroll
            for (int off = 1; off < 16; off <<= 1) {
                pel += __shfl_xor(pel, off);
                per_ += __shfl_xor(per_, off);
            }
            if (m == 0) {
                int row = row0 + wm * 32 + i * 16 + quad * 4 + r;
                atomicAdd(&elb[row], pel);
                atomicAdd(&erb[row], per_);
            }
        }
}

// 64x128 block-tile MFMA GEMM, BK=64, 2x2 wave layout (layer 2).
__global__ __launch_bounds__(256) void gemm_mfma64x128(
    const __half* __restrict__ A, const __half* __restrict__ Bt,
    __half* __restrict__ C, int N, int K, int M,
    size_t sA, size_t sB, size_t sC,
    const float* __restrict__ aVec, size_t aStride,
    float* __restrict__ el, float* __restrict__ er) {
    int b = blockIdx.z;
    const unsigned short* Ag = (const unsigned short*)(A + (size_t)b * sA);
    const unsigned short* Bg = (const unsigned short*)(Bt + (size_t)b * sB);
    __half* Cg = C + (size_t)b * sC;
    const float* av = aVec + (size_t)b * aStride;

    __shared__ __align__(16) unsigned short As[64][72];
    __shared__ __align__(16) unsigned short Bs[128][72];

    const int tid = threadIdx.x;
    const int wave = tid >> 6, lane = tid & 63;
    const int wm = wave >> 1, wn = wave & 1;
    const int row0 = blockIdx.y * 64, col0 = blockIdx.x * 128;
    const int lr = tid >> 2;
    const int lo = (tid & 3) * 16;
    const int m = lane & 15, quad = lane >> 4;

    v4f acc[2][4];
    #pragma unroll
    for (int i = 0; i < 2; i++)
        #pragma unroll
        for (int c = 0; c < 4; c++) acc[i][c] = (v4f)(0.f);

    for (int k0 = 0; k0 < K; k0 += 64) {
        *(int4*)(&As[lr][lo]) =
            *(const int4*)(Ag + (size_t)(row0 + lr) * K + k0 + lo);
        *(int4*)(&As[lr][lo + 8]) =
            *(const int4*)(Ag + (size_t)(row0 + lr) * K + k0 + lo + 8);
        *(int4*)(&Bs[lr][lo]) =
            *(const int4*)(Bg + (size_t)(col0 + lr) * K + k0 + lo);
        *(int4*)(&Bs[lr][lo + 8]) =
            *(const int4*)(Bg + (size_t)(col0 + lr) * K + k0 + lo + 8);
        *(int4*)(&Bs[lr + 64][lo]) =
            *(const int4*)(Bg + (size_t)(col0 + 64 + lr) * K + k0 + lo);
        *(int4*)(&Bs[lr + 64][lo + 8]) =
            *(const int4*)(Bg + (size_t)(col0 + 64 + lr) * K + k0 + lo + 8);
        __syncthreads();
        #pragma unroll
        for (int ks = 0; ks < 2; ks++) {
            v8s af[2], bfv[4];
            #pragma unroll
            for (int i = 0; i < 2; i++)
                af[i] = *(const v8s*)(&As[wm * 32 + i * 16 + m][ks * 32 + quad * 8]);
            #pragma unroll
            for (int c = 0; c < 4; c++)
                bfv[c] = *(const v8s*)(&Bs[wn * 64 + c * 16 + m][ks * 32 + quad * 8]);
            #pragma unroll
            for (int i = 0; i < 2; i++)
                #pragma unroll
                for (int c = 0; c < 4; c++)
                    acc[i][c] = __builtin_amdgcn_mfma_f32_16x16x32_f16(
                        af[i], bfv[c], acc[i][c], 0, 0, 0);
        }
        __syncthreads();
    }
    #pragma unroll
    for (int i = 0; i < 2; i++)
        #pragma unroll
        for (int c = 0; c < 4; c++)
            #pragma unroll
            for (int r = 0; r < 4; r++) {
                int row = row0 + wm * 32 + i * 16 + quad * 4 + r;
                int col = col0 + wn * 64 + c * 16 + m;
                Cg[(size_t)row * M + col] = __float2half(acc[i][c][r]);
            }
    float ael[4], aer[4];
    #pragma unroll
    for (int c = 0; c < 4; c++) {
        ael[c] = av[col0 + wn * 64 + c * 16 + m];
        aer[c] = av[M + col0 + wn * 64 + c * 16 + m];
    }
    #pragma unroll
    for (int i = 0; i < 2; i++)
        #pragma unroll
        for (int r = 0; r < 4; r++) {
            float pel = 0.f, per_ = 0.f;
            #pragma unroll
            for (int c = 0; c < 4; c++) {
                pel += acc[i][c][r] * ael[c];
                per_ += acc[i][c][r] * aer[c];
            }
            #pragma unroll
            for (int off = 1; off < 16; off <<= 1) {
                pel += __shfl_xor(pel, off);
                per_ += __shfl_xor(per_, off);
            }
            if (m == 0) {
                int row = row0 + wm * 32 + i * 16 + quad * 4 + r;
                atomicAdd(&el[(size_t)b * N + row], pel);
                atomicAdd(&er[(size_t)b * N + row], per_);
            }
        }
}

// 16-row tile GEMM for the M=64 output layer (K=1024), grid=256 blocks.
__global__ __launch_bounds__(256) void gemm_mfma16(
    const __half* __restrict__ A, const __half* __restrict__ Bt,
    __half* __restrict__ C, int N, int K, int M,
    const float* __restrict__ aVec,
    float* __restrict__ el, float* __restrict__ er) {
    const unsigned short* Ag = (const unsigned short*)A;
    const unsigned short* Bg = (const unsigned short*)Bt;
    __half* Cg = C;
    const float* av = aVec;

    __shared__ __align__(16) unsigned short As[16][72];
    __shared__ __align__(16) unsigned short Bs[64][72];

    const int tid = threadIdx.x;
    const int wave = tid >> 6, lane = tid & 63;
    const int row0 = blockIdx.y * 16;
    const int m = lane & 15, quad = lane >> 4;

    v4f acc = (v4f)(0.f);

    for (int k0 = 0; k0 < K; k0 += 64) {
        if (tid < 128) {
            int ar = tid >> 3, ac = (tid & 7) * 8;
            *(int4*)(&As[ar][ac]) =
                *(const int4*)(Ag + (size_t)(row0 + ar) * K + k0 + ac);
        }
        {
            int br = tid >> 2, bc = (tid & 3) * 16;
            *(int4*)(&Bs[br][bc]) =
                *(const int4*)(Bg + (size_t)br * K + k0 + bc);
            *(int4*)(&Bs[br][bc + 8]) =
                *(const int4*)(Bg + (size_t)br * K + k0 + bc + 8);
        }
        __syncthreads();
        #pragma unroll
        for (int ks = 0; ks < 2; ks++) {
            v8s af = *(const v8s*)(&As[m][ks * 32 + quad * 8]);
            v8s bf = *(const v8s*)(&Bs[wave * 16 + m][ks * 32 + quad * 8]);
            acc = __builtin_amdgcn_mfma_f32_16x16x32_f16(af, bf, acc, 0, 0, 0);
        }
        __syncthreads();
    }
    #pragma unroll
    for (int r = 0; r < 4; r++) {
        int row = row0 + quad * 4 + r;
        int col = wave * 16 + m;
        Cg[(size_t)row * M + col] = __float2half(acc[r]);
    }
    float ael = av[wave * 16 + m];
    float aer = av[M + wave * 16 + m];
    #pragma unroll
    for (int r = 0; r < 4; r++) {
        float pel = acc[r] * ael;
        float per_ = acc[r] * aer;
        #pragma unroll
        for (int off = 1; off < 16; off <<= 1) {
            pel += __shfl_xor(pel, off);
            per_ += __shfl_xor(per_, off);
        }
        if (m == 0) {
            int row = row0 + quad * 4 + r;
            atomicAdd(&el[row], pel);
            atomicAdd(&er[row], per_);
        }
    }
}

// Masked softmax + fp16 gather. Two waves/block, wave-per-task, XCD-pinned.
// attn_vec<256> is at its scattered-gather ceiling (~22 TB/s effective L2).
template<int D, int ACT, int HEADS, int FUSE>
__global__ __launch_bounds__(128) void attn_vec(
    const __half* __restrict__ Wh, const float* __restrict__ el,
    const float* __restrict__ er, const int* __restrict__ colIdx,
    const int* __restrict__ deg, __half* __restrict__ out,
    int N, size_t sWh, size_t sOut, int outRowStride,
    const float* __restrict__ wo1, const float* __restrict__ ao1,
    float* __restrict__ o2wh, float* __restrict__ el4, float* __restrict__ er4) {
    constexpr int LPN = D / 8;
    constexpr int SUBS = 64 / LPN;
    constexpr int PER_WAVE = SUBS * 4;
    constexpr int STEP = PER_WAVE * 2;

    const int tid = threadIdx.x;
    const int wave = tid >> 6, lane = tid & 63;
    int b, row;
    if (HEADS == 4) {
        int xcd = blockIdx.x & 7;
        b = xcd >> 1;
        row = ((xcd & 1) << 11) + ((blockIdx.x >> 3) << 1) + wave;
    } else {
        b = 0;
        row = blockIdx.x * 2 + wave;
    }

    const __half* whb = Wh + (size_t)b * sWh;
    const float* erb = er + (size_t)b * N;
    const float eln = el[(size_t)b * N + row];
    const int dc = deg[row];
    const int dcp = (dc + STEP - 1) & ~(STEP - 1);
    const int* ci = colIdx + (size_t)row * MAXDEG;

    __shared__ __align__(16) float2 spc[2][MAXDEG];
    float2* sp = spc[wave];

    float sreg[8];
    int jreg[8];
    float mx = -3.4e38f;
    #pragma unroll
    for (int s8 = 0; s8 < 8; s8++) {
        int k = s8 * 64 + lane;
        if (k < dc) {
            int j = ci[k];
            float s = eln + erb[j];
            s = fmaxf(s, 0.2f * s);
            sreg[s8] = s;
            jreg[s8] = j * (D * 2);
            mx = fmaxf(mx, s);
        }
    }
    #pragma unroll
    for (int off = 1; off < 64; off <<= 1) mx = fmaxf(mx, __shfl_xor(mx, off));

    float l = 0.f;
    #pragma unroll
    for (int s8 = 0; s8 < 8; s8++) {
        int k = s8 * 64 + lane;
        if (k < dc) {
            float p = __expf(sreg[s8] - mx);
            l += p;
            unsigned int pu = __half_as_ushort(__float2half(p));
            sp[k] = make_float2(__int_as_float(pu | (pu << 16)),
                                __int_as_float(jreg[s8]));
        }
    }
    for (int k = dc + lane; k < dcp; k += 64)
        sp[k] = make_float2(__int_as_float(0), __int_as_float(0));
    #pragma unroll
    for (int off = 1; off < 64; off <<= 1) l += __shfl_xor(l, off);
    const float inv = 1.f / l;

    asm volatile("s_waitcnt lgkmcnt(0)" ::: "memory");

    const int sub = lane / LPN;
    const int dl = (lane % LPN) * 8;
    const char* wp = (const char*)(whb + dl);

    union HU { unsigned int u; h2 h; };
    union R4 { uint4 u; h2 h[4]; };

    h2 a0[4], a1[4], a2[4], a3[4];
    #pragma unroll
    for (int i = 0; i < 4; i++) {
        a0[i] = (h2)(_Float16)0; a1[i] = (h2)(_Float16)0;
        a2[i] = (h2)(_Float16)0; a3[i] = (h2)(_Float16)0;
    }

    for (int k = sub * 4; k < dcp; k += STEP) {
        float4 pA = *(const float4*)(&sp[k]);
        float4 pB = *(const float4*)(&sp[k + 2]);
        float4 pC = *(const float4*)(&sp[k + PER_WAVE]);
        float4 pD = *(const float4*)(&sp[k + PER_WAVE + 2]);
        R4 r0, r1, r2, r3, r4, r5, r6, r7;
        r0.u = *(const uint4*)(wp + __float_as_int(pA.y));
        r1.u = *(const uint4*)(wp + __float_as_int(pA.w));
        r2.u = *(const uint4*)(wp + __float_as_int(pB.y));
        r3.u = *(const uint4*)(wp + __float_as_int(pB.w));
        r4.u = *(const uint4*)(wp + __float_as_int(pC.y));
        r5.u = *(const uint4*)(wp + __float_as_int(pC.w));
        r6.u = *(const uint4*)(wp + __float_as_int(pD.y));
        r7.u = *(const uint4*)(wp + __float_as_int(pD.w));
        HU p0, p1, p2, p3, p4, p5, p6, p7;
        p0.u = __float_as_int(pA.x);
        p1.u = __float_as_int(pA.z);
        p2.u = __float_as_int(pB.x);
        p3.u = __float_as_int(pB.z);
        p4.u = __float_as_int(pC.x);
        p5.u = __float_as_int(pC.z);
        p6.u = __float_as_int(pD.x);
        p7.u = __float_as_int(pD.z);
        #pragma unroll
        for (int i = 0; i < 4; i++) {
            a0[i] += p0.h * r0.h[i];
            a1[i] += p2.h * r2.h[i];
            a2[i] += p4.h * r4.h[i];
            a3[i] += p6.h * r6.h[i];
        }
        #pragma unroll
        for (int i = 0; i < 4; i++) {
            a0[i] += p1.h * r1.h[i];
            a1[i] += p3.h * r3.h[i];
            a2[i] += p5.h * r5.h[i];
            a3[i] += p7.h * r7.h[i];
        }
    }
    #pragma unroll
    for (int i = 0; i < 4; i++) a0[i] += (a1[i] + (a2[i] + a3[i]));
    #pragma unroll
    for (int off = LPN; off < 64; off <<= 1)
        #pragma unroll
        for (int i = 0; i < 4; i++) {
            HU t, s;
            t.h = a0[i];
            s.u = __shfl_xor((int)t.u, off);
            a0[i] += s.h;
        }

    if (FUSE) {
        if (sub == 0) {
            float t = 0.f;
            #pragma unroll
            for (int i = 0; i < 4; i++) {
                t += (float)a0[i][0] * inv * wo1[dl + 2 * i];
                t += (float)a0[i][1] * inv * wo1[dl + 2 * i + 1];
            }
            #pragma unroll
            for (int off = 1; off < LPN; off <<= 1) t += __shfl_xor(t, off);
            if (lane == 0) {
                o2wh[row] = t;
                el4[row] = t * ao1[0];
                er4[row] = t * ao1[1];
            }
        }
        return;
    }
    if (sub == 0) {
        __half hv[8];
        #pragma unroll
        for (int i = 0; i < 4; i++) {
            float v0 = (float)a0[i][0] * inv;
            float v1 = (float)a0[i][1] * inv;
            if (ACT == 1) {
                v0 = (v0 > 0.f) ? v0 : expm1f(v0);
                v1 = (v1 > 0.f) ? v1 : expm1f(v1);
            }
            hv[2 * i]     = __float2half(v0);
            hv[2 * i + 1] = __float2half(v1);
        }
        *(uint4*)(out + (size_t)b * sOut + (size_t)row * outRowStride + dl) =
            *(const uint4*)hv;
    }
}

// D==1 attention + elu + degreeNN fused (one block per row).
__global__ void attn_d1_deg(const float* __restrict__ o2wh, const float* __restrict__ el,
                            const float* __restrict__ er, const int* __restrict__ colIdx,
                            const int* __restrict__ deg, const float* __restrict__ dv,
                            const float* __restrict__ dW, const float* __restrict__ dW0,
                            const float* __restrict__ dW1, const float* __restrict__ dW01,
                            const float* __restrict__ dW2, const float* __restrict__ dW02,
                            const float* __restrict__ dV, const float* __restrict__ dV0,
                            float* __restrict__ out, int N) {
    int row = blockIdx.x, tid = threadIdx.x;
    const float eln = el[row];
    const int dc = deg[row];
    const int* ci = colIdx + (size_t)row * MAXDEG;
    __shared__ float sp[MAXDEG];
    __shared__ int sc[MAXDEG];
    float mx = -3.4e38f;
    for (int k = tid; k < dc; k += blockDim.x) {
        int j = ci[k];
        sc[k] = j;
        float s = eln + er[j];
        s = fmaxf(s, 0.2f * s);
        sp[k] = s;
        mx = fmaxf(mx, s);
    }
    mx = blockReduceMax(mx);
    float l = 0.f, acc = 0.f;
    for (int k = tid; k < dc; k += blockDim.x) {
        float p = __expf(sp[k] - mx);
        l += p;
        acc += p * o2wh[sc[k]];
    }
    l = blockReduceSum(l);
    acc = blockReduceSum(acc);
    if (tid == 0) {
        float h = acc / l;
        h = (h > 0.f) ? h : expm1f(h);
        float d = dv[row];
        float t0[10], t1[20], t2[10];
        #pragma unroll
        for (int i = 0; i < 10; i++)
            t0[i] = leaky(h * dW[i] + d * dW[10 + i] + dW0[i]);
        #pragma unroll
        for (int j = 0; j < 20; j++) {
            float s = dW01[j];
            #pragma unroll
            for (int i = 0; i < 10; i++) s += t0[i] * dW1[i * 20 + j];
            t1[j] = leaky(s);
        }
        #pragma unroll
        for (int j = 0; j < 10; j++) {
            float s = dW02[j];
            #pragma unroll
            for (int i = 0; i < 20; i++) s += t1[i] * dW2[i * 10 + j];
            t2[j] = leaky(s);
        }
        float o = dV0[0];
        #pragma unroll
        for (int i = 0; i < 10; i++) o += t2[i] * dV[i];
        out[row] = leaky(o);
    }
}

// ---------------- launch ----------------
extern "C" void kernel_launch(void* const* d_in, const int* in_sizes, int n_in,
                              void* d_out, int out_size, void* d_ws, size_t ws_size,
                              hipStream_t stream) {
    const int N = 4096, F = 512, H = 4, D1 = 256, O1 = 64;
    const float* x     = (const float*)d_in[0];
    const float* adj   = (const float*)d_in[1];
    const int*   obs   = (const int*)  d_in[2];
    const float* s_mat = (const float*)d_in[3];
    const float* theta = (const float*)d_in[4];
    const float* Wh0   = (const float*)d_in[5];
    const float* ah0   = (const float*)d_in[6];
    const float* Wh1   = (const float*)d_in[7];
    const float* ah1   = (const float*)d_in[8];
    const float* Wo0   = (const float*)d_in[9];
    const float* ao0   = (const float*)d_in[10];
    const float* Wo1   = (const float*)d_in[11];
    const float* ao1   = (const float*)d_in[12];
    const float* dWp   = (const float*)d_in[13];
    const float* dW0p  = (const float*)d_in[14];
    const float* dW1p  = (const float*)d_in[15];
    const float* dW01p = (const float*)d_in[16];
    const float* dW2p  = (const float*)d_in[17];
    const float* dW02p = (const float*)d_in[18];
    const float* dVp   = (const float*)d_in[19];
    const float* dV0p  = (const float*)d_in[20];
    float* outp = (float*)d_out;

    char* ws = (char*)d_ws;
    auto alloc = [&](size_t bytes) {
        char* p = ws;
        ws += (bytes + 255) & ~(size_t)255;
        return p;
    };
    __half* hin  = (__half*)alloc((size_t)N * F * 2);
    __half* whA  = (__half*)alloc((size_t)H * N * D1 * 2);
    __half* hb   = (__half*)alloc((size_t)H * N * D1 * 2);
    __half* hcat = (__half*)alloc((size_t)N * H * D1 * 2);
    __half* o1Wh = (__half*)alloc((size_t)N * O1 * 2);
    float* o2Wh  = (float*)alloc((size_t)N * 4);
    __half* Wh0t = (__half*)alloc((size_t)H * F * D1 * 2);
    __half* Wh1t = (__half*)alloc((size_t)H * D1 * D1 * 2);
    __half* Wo0t = (__half*)alloc((size_t)H * D1 * O1 * 2);
    int elerN = 4 * H * N + 2 * N;
    float* elerZ = (float*)alloc((size_t)elerN * 4);
    float* el1 = elerZ;
    float* er1 = el1 + H * N;
    float* el2 = er1 + H * N;
    float* er2 = el2 + H * N;
    float* el3 = er2 + H * N;
    float* er3 = el3 + N;
    float* el4 = (float*)alloc((size_t)N * 4);
    float* er4 = (float*)alloc((size_t)N * 4);
    float* dv  = (float*)alloc((size_t)N * 4);
    int* colIdx = (int*)alloc((size_t)N * MAXDEG * 4);
    int* deg    = (int*)alloc((size_t)N * 4);

    // ----- prep (hin, transposes, zeroing) -----
    pre_small<<<1024 + 72 + 208, 256, 0, stream>>>(
        x, obs, theta, Wh0, Wh1, Wo0, hin, Wh0t, Wh1t, Wo0t, elerZ, elerN);

    // ----- layer-1 GEMM (512 blocks, FIRST) ∥ CSR build (4096 blocks) -----
    gemm1_csr<<<512 + 4096, 256, 0, stream>>>(
        hin, Wh0t, whA, ah0, el1, er1,
        adj, s_mat, colIdx, deg, dv, N);
    attn_vec<256, 1, 4, 0><<<(N * H) / 2, 128, 0, stream>>>(
        whA, el1, er1, colIdx, deg, hb,
        N, (size_t)N * D1, (size_t)N * D1, D1,
        nullptr, nullptr, nullptr, nullptr, nullptr);

    // ----- multi-head layer 2 (D=256, elu) -> hcat interleaved -----
    gemm_mfma64x128<<<dim3(D1 / 128, N / 64, H), 256, 0, stream>>>(
        hb, Wh1t, whA, N, D1, D1, (size_t)N * D1, (size_t)D1 * D1, (size_t)N * D1,
        ah1, (size_t)2 * D1, el2, er2);
    attn_vec<256, 1, 4, 0><<<(N * H) / 2, 128, 0, stream>>>(
        whA, el2, er2, colIdx, deg, hcat,
        N, (size_t)N * D1, (size_t)D1, H * D1,
        nullptr, nullptr, nullptr, nullptr, nullptr);

    // ----- output layer 1 (D=64, no act) + fused matvec (Wo1) -----
    gemm_mfma16<<<dim3(1, N / 16, 1), 256, 0, stream>>>(
        hcat, Wo0t, o1Wh, N, H * D1, O1,
        ao0, el3, er3);
    attn_vec<64, 0, 1, 1><<<N / 2, 128, 0, stream>>>(
        o1Wh, el3, er3, colIdx, deg, nullptr,
        N, 0, 0, O1,
        Wo1, ao1, o2Wh, el4, er4);

    // ----- output layer 2 (D=1) + elu + degreeNN -----
    attn_d1_deg<<<N, 256, 0, stream>>>(o2Wh, el4, er4, colIdx, deg, dv,
        dWp, dW0p, dW1p, dW01p, dW2p, dW02p, dVp, dV0p, outp, N);
}